// Round 18
// baseline (201.025 us; speedup 1.0000x reference)
//
#include <hip/hip_runtime.h>
#include <math.h>

// Equivariant graph attention (Transformer_79302276153378), MI355X.
// Round 18: r17 + (a) node_fused 2 waves/node (8 edges in flight; halves the
// dependent src->nf16 gather chain), cross-wave merge in LDS; (b) scanB folded
// into scanC (per-block 256-thread reduction over bsum). 7 dispatches.

constexpr int NN = 20000;
constexpr int NE = 320000;
constexpr float INV3      = 0.57735026918962576f;  // 1/sqrt(3)
constexpr float INV_SQRT8 = 0.35355339059327373f;  // 1/sqrt(R_DIM)

typedef __attribute__((ext_vector_type(8))) short bf16x8;
typedef __attribute__((ext_vector_type(4))) float f32x4;

__device__ __forceinline__ float gelu_tanh(float p) {
    float y = 0.7978845608028654f * (p + 0.044715f * p * p * p);
    return p / (1.0f + __expf(-2.0f * y));
}
__device__ __forceinline__ ushort bf16_rn(float f) {
    unsigned u = __float_as_uint(f);
    unsigned r = (u + 0x7FFFu + ((u >> 16) & 1u)) >> 16;
    return (ushort)r;
}
__device__ __forceinline__ float bf16_f(ushort h) {
    return __uint_as_float(((unsigned)h) << 16);
}

// ---------------- prep: t (fp32) + nf16 + w2img + z/cnt zero ----------------
__global__ __launch_bounds__(256) void prep_kernel(
    const float* __restrict__ node_f,
    const float* __restrict__ w_ss,
    const float* __restrict__ w_vv,
    const float* __restrict__ k_w2,
    const float* __restrict__ v_w2,
    float* __restrict__ t,            // (NN,32,8) fp32
    ushort* __restrict__ nf16,        // (NN,32) ushort4
    ushort* __restrict__ w2img,       // 2 x 8192 pre-swizzled bf16
    float* __restrict__ z,
    int* __restrict__ cnt)
{
    const int tid = threadIdx.x;
    const int idx = blockIdx.x * 256 + tid;
    if (blockIdx.x < 64) {            // w2img side-job (16384 elems)
        const int i = idx;
        const int ph = i >> 13, r = i & 8191;
        const int k = r >> 7, n = r & 127;
        const float f = (ph ? v_w2 : k_w2)[r];
        const int sw = (n << 6) | (k ^ ((n & 7) << 3));
        w2img[(size_t)ph * 8192 + sw] = bf16_rn(f);
    }
    if (idx < NN) { z[idx] = 0.f; cnt[idx] = 0; }

    __shared__ float lws[2048];
    __shared__ float lwv[2048];
    for (int i = tid; i < 2048; i += 256) { lws[i] = w_ss[i]; lwv[i] = w_vv[i]; }
    __syncthreads();

    if (idx >= NN * 32) return;
    const int n = idx >> 5, v = idx & 31;
    const float* nf = node_f + (size_t)n * 128;

    float t0 = 0.f, t1 = 0.f;
    float tv00 = 0.f, tv01 = 0.f, tv02 = 0.f;
    float tv10 = 0.f, tv11 = 0.f, tv12 = 0.f;
    #pragma unroll
    for (int u = 0; u < 32; ++u) {
        const float s  = nf[u];
        const float vx = nf[32 + 3*u + 0];
        const float vy = nf[32 + 3*u + 1];
        const float vz = nf[32 + 3*u + 2];
        const float a = lws[u*32 + v];
        const float b = lws[1024 + u*32 + v];
        const float c = lwv[u*32 + v];
        const float d = lwv[1024 + u*32 + v];
        t0 = fmaf(s, a, t0);  t1 = fmaf(s, b, t1);
        tv00 = fmaf(vx, c, tv00); tv01 = fmaf(vy, c, tv01); tv02 = fmaf(vz, c, tv02);
        tv10 = fmaf(vx, d, tv10); tv11 = fmaf(vy, d, tv11); tv12 = fmaf(vz, d, tv12);
    }
    float4* o = (float4*)(t + (size_t)idx * 8);
    o[0] = make_float4(t0, t1, tv00 * INV3, tv01 * INV3);
    o[1] = make_float4(tv02 * INV3, tv10 * INV3, tv11 * INV3, tv12 * INV3);

    ushort4 pk2;                       // nf16 pack (L1-hot reloads)
    pk2.x = bf16_rn(nf[v]);
    pk2.y = bf16_rn(nf[32 + 3*v + 0]);
    pk2.z = bf16_rn(nf[32 + 3*v + 1]);
    pk2.w = bf16_rn(nf[32 + 3*v + 2]);
    ((ushort4*)nf16)[idx] = pk2;
}

// ---------------- CSR build ----------------
__global__ __launch_bounds__(256) void hist_kernel(
    const int* __restrict__ edst, int* __restrict__ cnt)
{
    const int e = blockIdx.x * 256 + threadIdx.x;
    if (e < NE) atomicAdd(&cnt[edst[e]], 1);
}

__global__ __launch_bounds__(256) void scanA_kernel(
    const int* __restrict__ cnt, int* __restrict__ rowptr, int* __restrict__ bsum)
{
    __shared__ int buf[256];
    const int i = blockIdx.x * 256 + threadIdx.x;
    const int v = (i < NN) ? cnt[i] : 0;
    buf[threadIdx.x] = v;
    __syncthreads();
    #pragma unroll
    for (int off = 1; off < 256; off <<= 1) {
        const int tc = (threadIdx.x >= off) ? buf[threadIdx.x - off] : 0;
        __syncthreads();
        buf[threadIdx.x] += tc;
        __syncthreads();
    }
    if (i < NN) rowptr[i] = buf[threadIdx.x] - v;       // local exclusive
    if (threadIdx.x == 255) bsum[blockIdx.x] = buf[255];
}

// scanBC: each block reduces bsum[0..blockIdx) itself (79 tiny reductions),
// applies the offset, writes rowptr/woff. scanB launch deleted.
__global__ __launch_bounds__(256) void scanBC_kernel(
    int* __restrict__ rowptr, const int* __restrict__ bsum, int* __restrict__ woff)
{
    __shared__ int red[256];
    const int tid = threadIdx.x;
    red[tid] = (tid < blockIdx.x) ? bsum[tid] : 0;      // blockIdx.x <= 78
    __syncthreads();
    #pragma unroll
    for (int off = 128; off >= 1; off >>= 1) {
        if (tid < off) red[tid] += red[tid + off];
        __syncthreads();
    }
    const int boff = red[0];
    const int i = blockIdx.x * 256 + tid;
    if (i < NN) {
        const int r = rowptr[i] + boff;
        rowptr[i] = r;
        woff[i] = r;
    }
    if (i == NN - 1) rowptr[NN] = NE;
}

// scatter: permute ALL edge data to CSR order (scattered writes, cheap kernel)
__global__ __launch_bounds__(256) void scatter_kernel(
    const int* __restrict__ esrc, const int* __restrict__ edst,
    const float* __restrict__ xattr, const float* __restrict__ eattr,
    const float* __restrict__ cutoff,
    int* __restrict__ woff,
    int* __restrict__ src_csr, int* __restrict__ dst_csr,
    float* __restrict__ xattr_csr, float* __restrict__ eattr_csr,
    float* __restrict__ cutoff_csr)
{
    const int e = blockIdx.x * 256 + threadIdx.x;
    if (e < NE) {
        const int d = edst[e];
        const int pos = atomicAdd(&woff[d], 1);
        src_csr[pos] = esrc[e];
        dst_csr[pos] = d;
        cutoff_csr[pos] = cutoff[e];
        const float4* xp = (const float4*)(xattr + (size_t)e * 8);
        float4* xo = (float4*)(xattr_csr + (size_t)pos * 8);
        xo[0] = xp[0]; xo[1] = xp[1];
        *(float4*)(eattr_csr + (size_t)pos * 4) = *(const float4*)(eattr + (size_t)e * 4);
    }
}

// ---------------- edge GEMM over CSR order + fused logit / A_v store ---------
// 64 CSR slots/block, 256 threads (4 waves x 16-edge M-tile). A-frag row=c,
// k=g*8(+32ks), swizzle ^((row&7)<<3); C: col=lane&15, row=g*4+reg.
// W2 hi + H hi only (single MFMA term); t fp32 (direct float4 loads).
__global__ __launch_bounds__(256, 3) void edge_gemm_kernel(
    const int*   __restrict__ src_csr,
    const int*   __restrict__ dst_csr,
    const float* __restrict__ xattr_csr,   // (NE,8) CSR
    const float* __restrict__ eattr_csr,   // (NE,4) CSR
    const float* __restrict__ cutoff_csr,  // (NE,)  CSR
    const ushort* __restrict__ nf16,       // (NN,32) ushort4 {s,vx,vy,vz}
    const float* __restrict__ k_w1,
    const float* __restrict__ v_w1,
    const ushort* __restrict__ w2img,      // pre-swizzled hi, 2 phases x 8192
    const float* __restrict__ t,           // (NN,256) fp32
    float* __restrict__ expw,              // (NE,) CSR order
    float* __restrict__ z,                 // (NN,) atomic
    ushort* __restrict__ Avb)              // (NE,128) bf16, CSR order
{
    __shared__ ushort W2h[8192];              // [n:128][k:64] swizzled, 16KB
    __shared__ ushort Hh[4096];               // [e:64][k:64] swizzled, 8KB
    __shared__ __align__(16) float xs[64][8];
    __shared__ __align__(16) float seat[64][4];
    __shared__ float  cut[64];
    __shared__ int    sdst[64], ssrc[64];

    const int tid  = threadIdx.x;
    const int e0   = blockIdx.x * 64;          // CSR base
    const int lane = tid & 63, wv = tid >> 6;
    const int c    = lane & 15, g = lane >> 4;
    const int j    = lane;                     // hidden index for H compute

    // linear staging (all CSR-ordered)
    ((float2*)xs)[tid] = ((const float2*)(xattr_csr + (size_t)e0 * 8))[tid];
    ((float*)seat)[tid] = eattr_csr[(size_t)e0 * 4 + tid];
    if (tid < 64) {
        cut[tid]  = cutoff_csr[e0 + tid];
        sdst[tid] = dst_csr[e0 + tid];
        ssrc[tid] = src_csr[e0 + tid];
    }

    for (int ph = 0; ph < 2; ++ph) {
        const float* w1 = ph ? v_w1 : k_w1;
        __syncthreads();   // staging visible (ph0) / prior frag reads done (ph1)

        // stage hi-only w2 image -> LDS (linear 16KB, conflict-free)
        {
            uint4* d = (uint4*)W2h;
            const uint4* s = (const uint4*)(w2img + (size_t)ph * 8192);
            #pragma unroll
            for (int i = tid; i < 1024; i += 256) d[i] = s[i];
        }
        // H = gelu(x @ w1 / sqrt(8)), bf16 hi, swizzled store
        {
            float w1c[8];
            #pragma unroll
            for (int r = 0; r < 8; ++r) w1c[r] = w1[r*64 + j];
            #pragma unroll
            for (int tt = 0; tt < 16; ++tt) {
                const int e = (tid >> 6) + 4*tt;
                const float4* xp = (const float4*)xs[e];
                const float4 x0 = xp[0], x1 = xp[1];
                float p = x0.x*w1c[0];
                p = fmaf(x0.y, w1c[1], p); p = fmaf(x0.z, w1c[2], p);
                p = fmaf(x0.w, w1c[3], p); p = fmaf(x1.x, w1c[4], p);
                p = fmaf(x1.y, w1c[5], p); p = fmaf(x1.z, w1c[6], p);
                p = fmaf(x1.w, w1c[7], p);
                const float h = gelu_tanh(p * INV_SQRT8);
                const int sw = (e << 6) | (j ^ ((e & 7) << 3));
                Hh[sw] = bf16_rn(h);
            }
        }
        __syncthreads();

        // MFMA: wave wv owns edges [eb, eb+16)
        const int eb = wv * 16;
        bf16x8 ah[2];
        #pragma unroll
        for (int ks = 0; ks < 2; ++ks) {
            const int row = eb + c;
            const int kb  = ks*32 + g*8;
            const int ad  = (row << 6) | (kb ^ ((row & 7) << 3));
            ah[ks] = *(const bf16x8*)&Hh[ad];
        }
        f32x4 accf[8];
        #pragma unroll
        for (int nt = 0; nt < 8; ++nt) accf[nt] = (f32x4){0.f, 0.f, 0.f, 0.f};
        #pragma unroll
        for (int nt = 0; nt < 8; ++nt) {
            const int n = nt*16 + c;
            #pragma unroll
            for (int ks = 0; ks < 2; ++ks) {
                const int kb = ks*32 + g*8;
                const int bd = (n << 6) | (kb ^ ((n & 7) << 3));
                const bf16x8 bh = *(const bf16x8*)&W2h[bd];
                accf[nt] = __builtin_amdgcn_mfma_f32_16x16x32_bf16(ah[ks], bh, accf[nt], 0, 0, 0);
            }
        }

        if (ph == 0) {
            // fused logit: logit = (P_e . t[dst]) * 0.125/64
            float contrib[4] = {0.f, 0.f, 0.f, 0.f};
            #pragma unroll
            for (int r = 0; r < 4; ++r) {
                const int el  = eb + g*4 + r;
                const int dst = sdst[el], src = ssrc[el];
                const float a0  = seat[el][0], a1x = seat[el][1];
                const float a1y = seat[el][2], a1z = seat[el][3];
                const float* tp = t + (size_t)dst * 256;
                const ushort4* np16 = (const ushort4*)nf16 + (size_t)src * 32;
                #pragma unroll
                for (int hf = 0; hf < 2; ++hf) {
                    const int v = c + 16*hf;
                    const float A0 = accf[0+hf][r], A1 = accf[2+hf][r];
                    const float A2 = accf[4+hf][r], A3 = accf[6+hf][r];
                    const float4 t4a = *(const float4*)(tp + v*8);
                    const float4 t4b = *(const float4*)(tp + v*8 + 4);
                    const ushort4 nv = np16[v];
                    const float s_v = bf16_f(nv.x);
                    const float vx = bf16_f(nv.y), vy = bf16_f(nv.z), vz = bf16_f(nv.w);
                    const float svd = vx*a1x + vy*a1y + vz*a1z;
                    contrib[r] += t4a.x * (A0 * s_v * a0)
                                + t4a.y * (A3 * svd * INV3)
                                + (A1 * s_v) * (t4a.z*a1x + t4a.w*a1y + t4b.x*a1z)
                                + (A2 * a0)  * (t4b.y*vx + t4b.z*vy + t4b.w*vz);
                }
            }
            #pragma unroll
            for (int r = 0; r < 4; ++r) {
                #pragma unroll
                for (int m = 1; m < 16; m <<= 1)
                    contrib[r] += __shfl_xor(contrib[r], m, 64);
            }
            if (c == 0) {
                #pragma unroll
                for (int r = 0; r < 4; ++r) {
                    const int el = eb + g*4 + r;
                    const float logit = contrib[r] * (0.125f / 64.0f);
                    const float ex = cut[el] * expf(logit);
                    expw[e0 + el] = ex;                 // CSR order
                    unsafeAtomicAdd(&z[sdst[el]], ex);
                }
            }
        } else {
            // store A_v bf16 at CSR index (node_fused reads linearly)
            #pragma unroll
            for (int nt = 0; nt < 8; ++nt) {
                #pragma unroll
                for (int r = 0; r < 4; ++r) {
                    const int el = eb + g*4 + r;
                    Avb[(size_t)(e0 + el)*128 + nt*16 + c] = bf16_rn(accf[nt][r]);
                }
            }
        }
    }
}

// ---------------- fused value segment-sum + node linears ----------------
// 2 nodes/block, 2 waves per node. Lane-half h + wave-half w2 => 4 edge slots,
// each with a 2-deep independent chain (8 edges in flight per node).
#define EDGE_ACC(KK, q0,q1,q2,q3,q4,q5,q6,q7)                                   \
    {                                                                           \
        const int kk_ = (KK);                                                   \
        const float cf_ = sqrtf(expw[kk_] * inv_z) * 0.125f;                    \
        const int src_ = src_csr[kk_];                                          \
        const float4 ea_ = *(const float4*)(eattr_csr + (size_t)kk_ * 4);       \
        const ushort4 nv_ = ((const ushort4*)nf16)[(size_t)src_ * 32 + v];      \
        const float sv_ = bf16_f(nv_.x);                                        \
        const float vx_ = bf16_f(nv_.y), vy_ = bf16_f(nv_.z), vz_ = bf16_f(nv_.w); \
        const ushort* av_ = Avb + (size_t)kk_ * 128;                            \
        const float A0_ = bf16_f(av_[v]),      A1_ = bf16_f(av_[32 + v]);       \
        const float A2_ = bf16_f(av_[64 + v]), A3_ = bf16_f(av_[96 + v]);       \
        q0 = fmaf(cf_ * A0_, sv_ * ea_.x, q0);                                  \
        q1 = fmaf(cf_ * A3_ * INV3, vx_*ea_.y + vy_*ea_.z + vz_*ea_.w, q1);     \
        const float t1_ = cf_ * A1_ * sv_, t2_ = cf_ * A2_ * ea_.x;             \
        q2 = fmaf(t1_, ea_.y, q2); q3 = fmaf(t1_, ea_.z, q3); q4 = fmaf(t1_, ea_.w, q4); \
        q5 = fmaf(t2_, vx_, q5);   q6 = fmaf(t2_, vy_, q6);   q7 = fmaf(t2_, vz_, q7); \
    }

__global__ __launch_bounds__(256) void node_fused_kernel(
    const int*   __restrict__ rowptr,
    const int*   __restrict__ src_csr,
    const float* __restrict__ eattr_csr,   // (NE,4) CSR
    const ushort* __restrict__ nf16,
    const ushort* __restrict__ Avb,        // (NE,128) CSR
    const float* __restrict__ expw,        // (NE,) CSR
    const float* __restrict__ z,
    const float* __restrict__ lin_ws,      // (64,32)
    const float* __restrict__ lin_wv,      // (64,32)
    float* __restrict__ out)               // (NN,128)
{
    __shared__ float sa[4][256];
    const int wv = threadIdx.x >> 6, lane = threadIdx.x & 63;
    const int pair = wv >> 1, w2 = wv & 1;     // node-in-block, wave-half
    const int n = blockIdx.x * 2 + pair;
    const int v = lane & 31, h = lane >> 5;

    float zv = z[n];
    if (zv == 0.f) zv = 1.f;
    const float inv_z = 1.0f / zv;
    const int k0 = rowptr[n], k1 = rowptr[n + 1];

    float c0 = 0.f, c1 = 0.f, c2 = 0.f, c3 = 0.f;
    float c4 = 0.f, c5 = 0.f, c6 = 0.f, c7 = 0.f;
    float d0 = 0.f, d1 = 0.f, d2 = 0.f, d3 = 0.f;
    float d4 = 0.f, d5 = 0.f, d6 = 0.f, d7 = 0.f;

    int kb = k0 + 2*w2 + h;                    // this lane's first edge slot
    for (; kb + 4 < k1; kb += 8) {
        EDGE_ACC(kb,     c0,c1,c2,c3,c4,c5,c6,c7);
        EDGE_ACC(kb + 4, d0,d1,d2,d3,d4,d5,d6,d7);
    }
    for (; kb < k1; kb += 4) {
        EDGE_ACC(kb, c0,c1,c2,c3,c4,c5,c6,c7);
    }
    c0 += d0; c1 += d1; c2 += d2; c3 += d3;
    c4 += d4; c5 += d5; c6 += d6; c7 += d7;

    c0 += __shfl_xor(c0, 32, 64); c1 += __shfl_xor(c1, 32, 64);
    c2 += __shfl_xor(c2, 32, 64); c3 += __shfl_xor(c3, 32, 64);
    c4 += __shfl_xor(c4, 32, 64); c5 += __shfl_xor(c5, 32, 64);
    c6 += __shfl_xor(c6, 32, 64); c7 += __shfl_xor(c7, 32, 64);

    // per-wave stash in acc layout; waves of a pair use slots 2p and 2p+1
    float* ad = sa[wv];
    if (lane < 32) {
        ad[v] = c0; ad[32 + v] = c1;
        ad[64  + 3*v] = c2; ad[65  + 3*v] = c3; ad[66  + 3*v] = c4;
        ad[160 + 3*v] = c5; ad[161 + 3*v] = c6; ad[162 + 3*v] = c7;
    }
    __syncthreads();

    // epilogue: waves with w2==0 handle their node; sum the two wave partials
    if (w2 == 0) {
        const float* aA = sa[pair*2];
        const float* aB = sa[pair*2 + 1];
        const int o = lane & 31, uh = lane >> 5;
        float os = 0.f, ov0 = 0.f, ov1 = 0.f, ov2 = 0.f;
        #pragma unroll
        for (int uu = 0; uu < 32; ++uu) {
            const int u = uh*32 + uu;
            os = fmaf(aA[u] + aB[u], lin_ws[u*32 + o], os);
            const float w = lin_wv[u*32 + o];
            ov0 = fmaf(aA[64 + 3*u + 0] + aB[64 + 3*u + 0], w, ov0);
            ov1 = fmaf(aA[64 + 3*u + 1] + aB[64 + 3*u + 1], w, ov1);
            ov2 = fmaf(aA[64 + 3*u + 2] + aB[64 + 3*u + 2], w, ov2);
        }
        os  += __shfl_xor(os, 32, 64);
        ov0 += __shfl_xor(ov0, 32, 64);
        ov1 += __shfl_xor(ov1, 32, 64);
        ov2 += __shfl_xor(ov2, 32, 64);
        if (lane < 32) {
            float* on = out + (size_t)n * 128;
            on[o]            = os  * 0.125f;
            on[32 + 3*o + 0] = ov0 * 0.125f;
            on[32 + 3*o + 1] = ov1 * 0.125f;
            on[32 + 3*o + 2] = ov2 * 0.125f;
        }
    }
}

extern "C" void kernel_launch(void* const* d_in, const int* in_sizes, int n_in,
                              void* d_out, int out_size, void* d_ws, size_t ws_size,
                              hipStream_t stream) {
    const int*   esrc    = (const int*)  d_in[0];
    const int*   edst    = (const int*)  d_in[1];
    const float* xattr   = (const float*)d_in[2];
    const float* eattr   = (const float*)d_in[3];
    const float* cutoff  = (const float*)d_in[4];
    const float* node_f  = (const float*)d_in[5];
    const float* k_w1    = (const float*)d_in[6];
    const float* k_w2    = (const float*)d_in[7];
    const float* v_w1    = (const float*)d_in[8];
    const float* v_w2    = (const float*)d_in[9];
    const float* w_ss    = (const float*)d_in[10];
    const float* w_vv    = (const float*)d_in[11];
    const float* lin_ws  = (const float*)d_in[12];
    const float* lin_wv  = (const float*)d_in[13];
    float* out = (float*)d_out;

    // ws (~128 MB): floats [t NN*256 | z NN | expw NE | xattr_csr NE*8 |
    //   eattr_csr NE*4 | cutoff_csr NE] | u16 [Avb NE*128 | w2img 16384 |
    //   nf16 NN*128] | ints [cnt | rowptr | woff | src_csr | dst_csr | bsum]
    float*  t          = (float*)d_ws;
    float*  z          = t + (size_t)NN * 256;
    float*  expw       = z + NN;
    float*  xattr_csr  = expw + NE;
    float*  eattr_csr  = xattr_csr + (size_t)NE * 8;
    float*  cutoff_csr = eattr_csr + (size_t)NE * 4;
    ushort* Avb        = (ushort*)(cutoff_csr + NE);
    ushort* w2img      = Avb + (size_t)NE * 128;
    ushort* nf16       = w2img + 16384;
    int*    cnt     = (int*)(nf16 + (size_t)NN * 128);
    int*    rowptr  = cnt + NN;
    int*    woff    = rowptr + NN + 1;
    int*    src_csr = woff + NN;
    int*    dst_csr = src_csr + NE;
    int*    bsum    = dst_csr + NE;

    prep_kernel<<<(NN*32 + 255)/256, 256, 0, stream>>>(
        node_f, w_ss, w_vv, k_w2, v_w2, t, nf16, w2img, z, cnt);

    hist_kernel<<<(NE + 255)/256, 256, 0, stream>>>(edst, cnt);
    scanA_kernel<<<(NN + 255)/256, 256, 0, stream>>>(cnt, rowptr, bsum);
    scanBC_kernel<<<(NN + 255)/256, 256, 0, stream>>>(rowptr, bsum, woff);
    scatter_kernel<<<(NE + 255)/256, 256, 0, stream>>>(
        esrc, edst, xattr, eattr, cutoff, woff,
        src_csr, dst_csr, xattr_csr, eattr_csr, cutoff_csr);

    edge_gemm_kernel<<<NE/64, 256, 0, stream>>>(
        src_csr, dst_csr, xattr_csr, eattr_csr, cutoff_csr, nf16,
        k_w1, v_w1, w2img, t, expw, z, Avb);

    node_fused_kernel<<<NN/2, 256, 0, stream>>>(
        rowptr, src_csr, eattr_csr, nf16, Avb, expw, z, lin_ws, lin_wv, out);
}

// Round 19
// 191.356 us; speedup vs baseline: 1.0505x; 1.0505x over previous
//
#include <hip/hip_runtime.h>
#include <math.h>

// Equivariant graph attention (Transformer_79302276153378), MI355X.
// Round 19: best-of configuration. r17's node_fused (4 nodes/block, lane-half
// pairs, 4-edge dual-chain unroll -- measured best) + r18's scanBC fold
// (7 dispatches). r18's 2-wave-per-node variant reverted (epilogue idled half
// the waves, stride-4 edge slots hurt locality: 194->201).

constexpr int NN = 20000;
constexpr int NE = 320000;
constexpr float INV3      = 0.57735026918962576f;  // 1/sqrt(3)
constexpr float INV_SQRT8 = 0.35355339059327373f;  // 1/sqrt(R_DIM)

typedef __attribute__((ext_vector_type(8))) short bf16x8;
typedef __attribute__((ext_vector_type(4))) float f32x4;

__device__ __forceinline__ float gelu_tanh(float p) {
    float y = 0.7978845608028654f * (p + 0.044715f * p * p * p);
    return p / (1.0f + __expf(-2.0f * y));
}
__device__ __forceinline__ ushort bf16_rn(float f) {
    unsigned u = __float_as_uint(f);
    unsigned r = (u + 0x7FFFu + ((u >> 16) & 1u)) >> 16;
    return (ushort)r;
}
__device__ __forceinline__ float bf16_f(ushort h) {
    return __uint_as_float(((unsigned)h) << 16);
}

// ---------------- prep: t (fp32) + nf16 + w2img + z/cnt zero ----------------
__global__ __launch_bounds__(256) void prep_kernel(
    const float* __restrict__ node_f,
    const float* __restrict__ w_ss,
    const float* __restrict__ w_vv,
    const float* __restrict__ k_w2,
    const float* __restrict__ v_w2,
    float* __restrict__ t,            // (NN,32,8) fp32
    ushort* __restrict__ nf16,        // (NN,32) ushort4
    ushort* __restrict__ w2img,       // 2 x 8192 pre-swizzled bf16
    float* __restrict__ z,
    int* __restrict__ cnt)
{
    const int tid = threadIdx.x;
    const int idx = blockIdx.x * 256 + tid;
    if (blockIdx.x < 64) {            // w2img side-job (16384 elems)
        const int i = idx;
        const int ph = i >> 13, r = i & 8191;
        const int k = r >> 7, n = r & 127;
        const float f = (ph ? v_w2 : k_w2)[r];
        const int sw = (n << 6) | (k ^ ((n & 7) << 3));
        w2img[(size_t)ph * 8192 + sw] = bf16_rn(f);
    }
    if (idx < NN) { z[idx] = 0.f; cnt[idx] = 0; }

    __shared__ float lws[2048];
    __shared__ float lwv[2048];
    for (int i = tid; i < 2048; i += 256) { lws[i] = w_ss[i]; lwv[i] = w_vv[i]; }
    __syncthreads();

    if (idx >= NN * 32) return;
    const int n = idx >> 5, v = idx & 31;
    const float* nf = node_f + (size_t)n * 128;

    float t0 = 0.f, t1 = 0.f;
    float tv00 = 0.f, tv01 = 0.f, tv02 = 0.f;
    float tv10 = 0.f, tv11 = 0.f, tv12 = 0.f;
    #pragma unroll
    for (int u = 0; u < 32; ++u) {
        const float s  = nf[u];
        const float vx = nf[32 + 3*u + 0];
        const float vy = nf[32 + 3*u + 1];
        const float vz = nf[32 + 3*u + 2];
        const float a = lws[u*32 + v];
        const float b = lws[1024 + u*32 + v];
        const float c = lwv[u*32 + v];
        const float d = lwv[1024 + u*32 + v];
        t0 = fmaf(s, a, t0);  t1 = fmaf(s, b, t1);
        tv00 = fmaf(vx, c, tv00); tv01 = fmaf(vy, c, tv01); tv02 = fmaf(vz, c, tv02);
        tv10 = fmaf(vx, d, tv10); tv11 = fmaf(vy, d, tv11); tv12 = fmaf(vz, d, tv12);
    }
    float4* o = (float4*)(t + (size_t)idx * 8);
    o[0] = make_float4(t0, t1, tv00 * INV3, tv01 * INV3);
    o[1] = make_float4(tv02 * INV3, tv10 * INV3, tv11 * INV3, tv12 * INV3);

    ushort4 pk2;                       // nf16 pack (L1-hot reloads)
    pk2.x = bf16_rn(nf[v]);
    pk2.y = bf16_rn(nf[32 + 3*v + 0]);
    pk2.z = bf16_rn(nf[32 + 3*v + 1]);
    pk2.w = bf16_rn(nf[32 + 3*v + 2]);
    ((ushort4*)nf16)[idx] = pk2;
}

// ---------------- CSR build ----------------
__global__ __launch_bounds__(256) void hist_kernel(
    const int* __restrict__ edst, int* __restrict__ cnt)
{
    const int e = blockIdx.x * 256 + threadIdx.x;
    if (e < NE) atomicAdd(&cnt[edst[e]], 1);
}

__global__ __launch_bounds__(256) void scanA_kernel(
    const int* __restrict__ cnt, int* __restrict__ rowptr, int* __restrict__ bsum)
{
    __shared__ int buf[256];
    const int i = blockIdx.x * 256 + threadIdx.x;
    const int v = (i < NN) ? cnt[i] : 0;
    buf[threadIdx.x] = v;
    __syncthreads();
    #pragma unroll
    for (int off = 1; off < 256; off <<= 1) {
        const int tc = (threadIdx.x >= off) ? buf[threadIdx.x - off] : 0;
        __syncthreads();
        buf[threadIdx.x] += tc;
        __syncthreads();
    }
    if (i < NN) rowptr[i] = buf[threadIdx.x] - v;       // local exclusive
    if (threadIdx.x == 255) bsum[blockIdx.x] = buf[255];
}

// scanBC: each block reduces bsum[0..blockIdx) itself, applies offset.
__global__ __launch_bounds__(256) void scanBC_kernel(
    int* __restrict__ rowptr, const int* __restrict__ bsum, int* __restrict__ woff)
{
    __shared__ int red[256];
    const int tid = threadIdx.x;
    red[tid] = (tid < blockIdx.x) ? bsum[tid] : 0;      // blockIdx.x <= 78
    __syncthreads();
    #pragma unroll
    for (int off = 128; off >= 1; off >>= 1) {
        if (tid < off) red[tid] += red[tid + off];
        __syncthreads();
    }
    const int boff = red[0];
    const int i = blockIdx.x * 256 + tid;
    if (i < NN) {
        const int r = rowptr[i] + boff;
        rowptr[i] = r;
        woff[i] = r;
    }
    if (i == NN - 1) rowptr[NN] = NE;
}

// scatter: permute ALL edge data to CSR order (scattered writes, cheap kernel)
__global__ __launch_bounds__(256) void scatter_kernel(
    const int* __restrict__ esrc, const int* __restrict__ edst,
    const float* __restrict__ xattr, const float* __restrict__ eattr,
    const float* __restrict__ cutoff,
    int* __restrict__ woff,
    int* __restrict__ src_csr, int* __restrict__ dst_csr,
    float* __restrict__ xattr_csr, float* __restrict__ eattr_csr,
    float* __restrict__ cutoff_csr)
{
    const int e = blockIdx.x * 256 + threadIdx.x;
    if (e < NE) {
        const int d = edst[e];
        const int pos = atomicAdd(&woff[d], 1);
        src_csr[pos] = esrc[e];
        dst_csr[pos] = d;
        cutoff_csr[pos] = cutoff[e];
        const float4* xp = (const float4*)(xattr + (size_t)e * 8);
        float4* xo = (float4*)(xattr_csr + (size_t)pos * 8);
        xo[0] = xp[0]; xo[1] = xp[1];
        *(float4*)(eattr_csr + (size_t)pos * 4) = *(const float4*)(eattr + (size_t)e * 4);
    }
}

// ---------------- edge GEMM over CSR order + fused logit / A_v store ---------
// 64 CSR slots/block, 256 threads (4 waves x 16-edge M-tile). A-frag row=c,
// k=g*8(+32ks), swizzle ^((row&7)<<3); C: col=lane&15, row=g*4+reg.
// W2 hi + H hi only (single MFMA term); t fp32 (direct float4 loads).
__global__ __launch_bounds__(256, 3) void edge_gemm_kernel(
    const int*   __restrict__ src_csr,
    const int*   __restrict__ dst_csr,
    const float* __restrict__ xattr_csr,   // (NE,8) CSR
    const float* __restrict__ eattr_csr,   // (NE,4) CSR
    const float* __restrict__ cutoff_csr,  // (NE,)  CSR
    const ushort* __restrict__ nf16,       // (NN,32) ushort4 {s,vx,vy,vz}
    const float* __restrict__ k_w1,
    const float* __restrict__ v_w1,
    const ushort* __restrict__ w2img,      // pre-swizzled hi, 2 phases x 8192
    const float* __restrict__ t,           // (NN,256) fp32
    float* __restrict__ expw,              // (NE,) CSR order
    float* __restrict__ z,                 // (NN,) atomic
    ushort* __restrict__ Avb)              // (NE,128) bf16, CSR order
{
    __shared__ ushort W2h[8192];              // [n:128][k:64] swizzled, 16KB
    __shared__ ushort Hh[4096];               // [e:64][k:64] swizzled, 8KB
    __shared__ __align__(16) float xs[64][8];
    __shared__ __align__(16) float seat[64][4];
    __shared__ float  cut[64];
    __shared__ int    sdst[64], ssrc[64];

    const int tid  = threadIdx.x;
    const int e0   = blockIdx.x * 64;          // CSR base
    const int lane = tid & 63, wv = tid >> 6;
    const int c    = lane & 15, g = lane >> 4;
    const int j    = lane;                     // hidden index for H compute

    // linear staging (all CSR-ordered)
    ((float2*)xs)[tid] = ((const float2*)(xattr_csr + (size_t)e0 * 8))[tid];
    ((float*)seat)[tid] = eattr_csr[(size_t)e0 * 4 + tid];
    if (tid < 64) {
        cut[tid]  = cutoff_csr[e0 + tid];
        sdst[tid] = dst_csr[e0 + tid];
        ssrc[tid] = src_csr[e0 + tid];
    }

    for (int ph = 0; ph < 2; ++ph) {
        const float* w1 = ph ? v_w1 : k_w1;
        __syncthreads();   // staging visible (ph0) / prior frag reads done (ph1)

        // stage hi-only w2 image -> LDS (linear 16KB, conflict-free)
        {
            uint4* d = (uint4*)W2h;
            const uint4* s = (const uint4*)(w2img + (size_t)ph * 8192);
            #pragma unroll
            for (int i = tid; i < 1024; i += 256) d[i] = s[i];
        }
        // H = gelu(x @ w1 / sqrt(8)), bf16 hi, swizzled store
        {
            float w1c[8];
            #pragma unroll
            for (int r = 0; r < 8; ++r) w1c[r] = w1[r*64 + j];
            #pragma unroll
            for (int tt = 0; tt < 16; ++tt) {
                const int e = (tid >> 6) + 4*tt;
                const float4* xp = (const float4*)xs[e];
                const float4 x0 = xp[0], x1 = xp[1];
                float p = x0.x*w1c[0];
                p = fmaf(x0.y, w1c[1], p); p = fmaf(x0.z, w1c[2], p);
                p = fmaf(x0.w, w1c[3], p); p = fmaf(x1.x, w1c[4], p);
                p = fmaf(x1.y, w1c[5], p); p = fmaf(x1.z, w1c[6], p);
                p = fmaf(x1.w, w1c[7], p);
                const float h = gelu_tanh(p * INV_SQRT8);
                const int sw = (e << 6) | (j ^ ((e & 7) << 3));
                Hh[sw] = bf16_rn(h);
            }
        }
        __syncthreads();

        // MFMA: wave wv owns edges [eb, eb+16)
        const int eb = wv * 16;
        bf16x8 ah[2];
        #pragma unroll
        for (int ks = 0; ks < 2; ++ks) {
            const int row = eb + c;
            const int kb  = ks*32 + g*8;
            const int ad  = (row << 6) | (kb ^ ((row & 7) << 3));
            ah[ks] = *(const bf16x8*)&Hh[ad];
        }
        f32x4 accf[8];
        #pragma unroll
        for (int nt = 0; nt < 8; ++nt) accf[nt] = (f32x4){0.f, 0.f, 0.f, 0.f};
        #pragma unroll
        for (int nt = 0; nt < 8; ++nt) {
            const int n = nt*16 + c;
            #pragma unroll
            for (int ks = 0; ks < 2; ++ks) {
                const int kb = ks*32 + g*8;
                const int bd = (n << 6) | (kb ^ ((n & 7) << 3));
                const bf16x8 bh = *(const bf16x8*)&W2h[bd];
                accf[nt] = __builtin_amdgcn_mfma_f32_16x16x32_bf16(ah[ks], bh, accf[nt], 0, 0, 0);
            }
        }

        if (ph == 0) {
            // fused logit: logit = (P_e . t[dst]) * 0.125/64
            float contrib[4] = {0.f, 0.f, 0.f, 0.f};
            #pragma unroll
            for (int r = 0; r < 4; ++r) {
                const int el  = eb + g*4 + r;
                const int dst = sdst[el], src = ssrc[el];
                const float a0  = seat[el][0], a1x = seat[el][1];
                const float a1y = seat[el][2], a1z = seat[el][3];
                const float* tp = t + (size_t)dst * 256;
                const ushort4* np16 = (const ushort4*)nf16 + (size_t)src * 32;
                #pragma unroll
                for (int hf = 0; hf < 2; ++hf) {
                    const int v = c + 16*hf;
                    const float A0 = accf[0+hf][r], A1 = accf[2+hf][r];
                    const float A2 = accf[4+hf][r], A3 = accf[6+hf][r];
                    const float4 t4a = *(const float4*)(tp + v*8);
                    const float4 t4b = *(const float4*)(tp + v*8 + 4);
                    const ushort4 nv = np16[v];
                    const float s_v = bf16_f(nv.x);
                    const float vx = bf16_f(nv.y), vy = bf16_f(nv.z), vz = bf16_f(nv.w);
                    const float svd = vx*a1x + vy*a1y + vz*a1z;
                    contrib[r] += t4a.x * (A0 * s_v * a0)
                                + t4a.y * (A3 * svd * INV3)
                                + (A1 * s_v) * (t4a.z*a1x + t4a.w*a1y + t4b.x*a1z)
                                + (A2 * a0)  * (t4b.y*vx + t4b.z*vy + t4b.w*vz);
                }
            }
            #pragma unroll
            for (int r = 0; r < 4; ++r) {
                #pragma unroll
                for (int m = 1; m < 16; m <<= 1)
                    contrib[r] += __shfl_xor(contrib[r], m, 64);
            }
            if (c == 0) {
                #pragma unroll
                for (int r = 0; r < 4; ++r) {
                    const int el = eb + g*4 + r;
                    const float logit = contrib[r] * (0.125f / 64.0f);
                    const float ex = cut[el] * expf(logit);
                    expw[e0 + el] = ex;                 // CSR order
                    unsafeAtomicAdd(&z[sdst[el]], ex);
                }
            }
        } else {
            // store A_v bf16 at CSR index (node_fused reads linearly)
            #pragma unroll
            for (int nt = 0; nt < 8; ++nt) {
                #pragma unroll
                for (int r = 0; r < 4; ++r) {
                    const int el = eb + g*4 + r;
                    Avb[(size_t)(e0 + el)*128 + nt*16 + c] = bf16_rn(accf[nt][r]);
                }
            }
        }
    }
}

// ---------------- fused value segment-sum + node linears ----------------
// 4 waves/block, wave per node. Uniform lanes; 4 edges/iter (2 per lane-half,
// independent accumulator chains); shfl_xor(32) merges halves at end.
#define EDGE_ACC(KK, q0,q1,q2,q3,q4,q5,q6,q7)                                   \
    {                                                                           \
        const int kk_ = (KK);                                                   \
        const float cf_ = sqrtf(expw[kk_] * inv_z) * 0.125f;                    \
        const int src_ = src_csr[kk_];                                          \
        const float4 ea_ = *(const float4*)(eattr_csr + (size_t)kk_ * 4);       \
        const ushort4 nv_ = ((const ushort4*)nf16)[(size_t)src_ * 32 + v];      \
        const float sv_ = bf16_f(nv_.x);                                        \
        const float vx_ = bf16_f(nv_.y), vy_ = bf16_f(nv_.z), vz_ = bf16_f(nv_.w); \
        const ushort* av_ = Avb + (size_t)kk_ * 128;                            \
        const float A0_ = bf16_f(av_[v]),      A1_ = bf16_f(av_[32 + v]);       \
        const float A2_ = bf16_f(av_[64 + v]), A3_ = bf16_f(av_[96 + v]);       \
        q0 = fmaf(cf_ * A0_, sv_ * ea_.x, q0);                                  \
        q1 = fmaf(cf_ * A3_ * INV3, vx_*ea_.y + vy_*ea_.z + vz_*ea_.w, q1);     \
        const float t1_ = cf_ * A1_ * sv_, t2_ = cf_ * A2_ * ea_.x;             \
        q2 = fmaf(t1_, ea_.y, q2); q3 = fmaf(t1_, ea_.z, q3); q4 = fmaf(t1_, ea_.w, q4); \
        q5 = fmaf(t2_, vx_, q5);   q6 = fmaf(t2_, vy_, q6);   q7 = fmaf(t2_, vz_, q7); \
    }

__global__ __launch_bounds__(256) void node_fused_kernel(
    const int*   __restrict__ rowptr,
    const int*   __restrict__ src_csr,
    const float* __restrict__ eattr_csr,   // (NE,4) CSR
    const ushort* __restrict__ nf16,
    const ushort* __restrict__ Avb,        // (NE,128) CSR
    const float* __restrict__ expw,        // (NE,) CSR
    const float* __restrict__ z,
    const float* __restrict__ lin_ws,      // (64,32)
    const float* __restrict__ lin_wv,      // (64,32)
    float* __restrict__ out)               // (NN,128)
{
    __shared__ float sa[4][256];
    const int wv = threadIdx.x >> 6, lane = threadIdx.x & 63;
    const int n = blockIdx.x * 4 + wv;
    const int v = lane & 31, h = lane >> 5;

    float zv = z[n];
    if (zv == 0.f) zv = 1.f;
    const float inv_z = 1.0f / zv;
    const int k0 = rowptr[n], k1 = rowptr[n + 1];

    float c0 = 0.f, c1 = 0.f, c2 = 0.f, c3 = 0.f;
    float c4 = 0.f, c5 = 0.f, c6 = 0.f, c7 = 0.f;
    float d0 = 0.f, d1 = 0.f, d2 = 0.f, d3 = 0.f;
    float d4 = 0.f, d5 = 0.f, d6 = 0.f, d7 = 0.f;

    int kb = k0;
    for (; kb + 3 < k1; kb += 4) {
        EDGE_ACC(kb + h,     c0,c1,c2,c3,c4,c5,c6,c7);
        EDGE_ACC(kb + 2 + h, d0,d1,d2,d3,d4,d5,d6,d7);
    }
    for (; kb < k1; kb += 2) {
        const int kk = kb + h;
        if (kk < k1) EDGE_ACC(kk, c0,c1,c2,c3,c4,c5,c6,c7);
    }
    c0 += d0; c1 += d1; c2 += d2; c3 += d3;
    c4 += d4; c5 += d5; c6 += d6; c7 += d7;

    c0 += __shfl_xor(c0, 32, 64); c1 += __shfl_xor(c1, 32, 64);
    c2 += __shfl_xor(c2, 32, 64); c3 += __shfl_xor(c3, 32, 64);
    c4 += __shfl_xor(c4, 32, 64); c5 += __shfl_xor(c5, 32, 64);
    c6 += __shfl_xor(c6, 32, 64); c7 += __shfl_xor(c7, 32, 64);

    // stash in acc layout: [0..31]=s0, [32..63]=s1, [64..159]=v0, [160..255]=v1
    float* ad = sa[wv];
    if (lane < 32) {
        ad[v] = c0; ad[32 + v] = c1;
        ad[64  + 3*v] = c2; ad[65  + 3*v] = c3; ad[66  + 3*v] = c4;
        ad[160 + 3*v] = c5; ad[161 + 3*v] = c6; ad[162 + 3*v] = c7;
    }
    __syncthreads();

    // epilogue: 64 lanes -> 32 outputs, u-range split by lane half
    const float* a8 = sa[wv];
    const int o = lane & 31, uh = lane >> 5;
    float os = 0.f, ov0 = 0.f, ov1 = 0.f, ov2 = 0.f;
    #pragma unroll
    for (int uu = 0; uu < 32; ++uu) {
        const int u = uh*32 + uu;
        os = fmaf(a8[u], lin_ws[u*32 + o], os);
        const float w = lin_wv[u*32 + o];
        ov0 = fmaf(a8[64 + 3*u + 0], w, ov0);
        ov1 = fmaf(a8[64 + 3*u + 1], w, ov1);
        ov2 = fmaf(a8[64 + 3*u + 2], w, ov2);
    }
    os  += __shfl_xor(os, 32, 64);
    ov0 += __shfl_xor(ov0, 32, 64);
    ov1 += __shfl_xor(ov1, 32, 64);
    ov2 += __shfl_xor(ov2, 32, 64);
    if (lane < 32) {
        float* on = out + (size_t)n * 128;
        on[o]            = os  * 0.125f;
        on[32 + 3*o + 0] = ov0 * 0.125f;
        on[32 + 3*o + 1] = ov1 * 0.125f;
        on[32 + 3*o + 2] = ov2 * 0.125f;
    }
}

extern "C" void kernel_launch(void* const* d_in, const int* in_sizes, int n_in,
                              void* d_out, int out_size, void* d_ws, size_t ws_size,
                              hipStream_t stream) {
    const int*   esrc    = (const int*)  d_in[0];
    const int*   edst    = (const int*)  d_in[1];
    const float* xattr   = (const float*)d_in[2];
    const float* eattr   = (const float*)d_in[3];
    const float* cutoff  = (const float*)d_in[4];
    const float* node_f  = (const float*)d_in[5];
    const float* k_w1    = (const float*)d_in[6];
    const float* k_w2    = (const float*)d_in[7];
    const float* v_w1    = (const float*)d_in[8];
    const float* v_w2    = (const float*)d_in[9];
    const float* w_ss    = (const float*)d_in[10];
    const float* w_vv    = (const float*)d_in[11];
    const float* lin_ws  = (const float*)d_in[12];
    const float* lin_wv  = (const float*)d_in[13];
    float* out = (float*)d_out;

    // ws (~128 MB): floats [t NN*256 | z NN | expw NE | xattr_csr NE*8 |
    //   eattr_csr NE*4 | cutoff_csr NE] | u16 [Avb NE*128 | w2img 16384 |
    //   nf16 NN*128] | ints [cnt | rowptr | woff | src_csr | dst_csr | bsum]
    float*  t          = (float*)d_ws;
    float*  z          = t + (size_t)NN * 256;
    float*  expw       = z + NN;
    float*  xattr_csr  = expw + NE;
    float*  eattr_csr  = xattr_csr + (size_t)NE * 8;
    float*  cutoff_csr = eattr_csr + (size_t)NE * 4;
    ushort* Avb        = (ushort*)(cutoff_csr + NE);
    ushort* w2img      = Avb + (size_t)NE * 128;
    ushort* nf16       = w2img + 16384;
    int*    cnt     = (int*)(nf16 + (size_t)NN * 128);
    int*    rowptr  = cnt + NN;
    int*    woff    = rowptr + NN + 1;
    int*    src_csr = woff + NN;
    int*    dst_csr = src_csr + NE;
    int*    bsum    = dst_csr + NE;

    prep_kernel<<<(NN*32 + 255)/256, 256, 0, stream>>>(
        node_f, w_ss, w_vv, k_w2, v_w2, t, nf16, w2img, z, cnt);

    hist_kernel<<<(NE + 255)/256, 256, 0, stream>>>(edst, cnt);
    scanA_kernel<<<(NN + 255)/256, 256, 0, stream>>>(cnt, rowptr, bsum);
    scanBC_kernel<<<(NN + 255)/256, 256, 0, stream>>>(rowptr, bsum, woff);
    scatter_kernel<<<(NE + 255)/256, 256, 0, stream>>>(
        esrc, edst, xattr, eattr, cutoff, woff,
        src_csr, dst_csr, xattr_csr, eattr_csr, cutoff_csr);

    edge_gemm_kernel<<<NE/64, 256, 0, stream>>>(
        src_csr, dst_csr, xattr_csr, eattr_csr, cutoff_csr, nf16,
        k_w1, v_w1, w2img, t, expw, z, Avb);

    node_fused_kernel<<<NN/4, 256, 0, stream>>>(
        rowptr, src_csr, eattr_csr, nf16, Avb, expw, z, lin_ws, lin_wv, out);
}